// Round 8
// baseline (823.241 us; speedup 1.0000x reference)
//
#include <hip/hip_runtime.h>
#include <hip/hip_bf16.h>
#include <cstdint>
#include <cstddef>

#define V_TEXT   256
#define V_TOTAL  4352
#define V_AUDIO  4096
#define B_       8
#define TQ_      800
#define TK_      128
#define T_TOK    1024
#define NSEQ     32
#define NEGF     (-1.0e9f)
#define K2       1.4426950408889634f   // 1/ln2
#define LN2      0.6931471805599453f
#define EB8      11.541560327111707f   // 8*K2
#define FNEGINF  (-3.0e38f)
#define CHK      40                    // timesteps per LDS chunk
#define NCH      20                    // 800/40

#define NB_REC   32
#define NB_LSE   6400                  // 25600 rows / 4 per block
#define NB_CE    2048                  // 8192 rows / 4 per block
#define NB_TOT   (NB_REC + NB_LSE + NB_CE)

// ws float-index layout (memset first 6400 bytes to 0 by host):
//  [0..31]          per-seq attn losses
//  [32+16n]         Cs[n] (float atomic accum of lneg, t<q)
//  [544+16n]        lse_done[n] (uint counter, target 200)
//  [1056+16s]       ce partial slots, s<32
//  [1568]           global done counter (uint)

template <int CTRL>
__device__ __forceinline__ float dpp_mov(float x, float old) {
    return __int_as_float(__builtin_amdgcn_update_dpp(
        __float_as_int(old), __float_as_int(x), CTRL, 0xf, 0xf, false));
}
__device__ __forceinline__ float dpp_shr1_old(float x, float old) {
    return dpp_mov<0x138>(x, old);      // wave_shr:1
}
__device__ __forceinline__ float lane_bcast(float x, int lane) {
    return __int_as_float(__builtin_amdgcn_readlane(__float_as_int(x), lane));
}
__device__ __forceinline__ float wave_max(float x) {
    x = fmaxf(x, dpp_mov<0x111>(x, FNEGINF));
    x = fmaxf(x, dpp_mov<0x112>(x, FNEGINF));
    x = fmaxf(x, dpp_mov<0x114>(x, FNEGINF));
    x = fmaxf(x, dpp_mov<0x118>(x, FNEGINF));
    x = fmaxf(x, dpp_mov<0x142>(x, FNEGINF));
    x = fmaxf(x, dpp_mov<0x143>(x, FNEGINF));
    return lane_bcast(x, 63);
}
__device__ __forceinline__ float wave_sum(float x) {
    x += dpp_mov<0x111>(x, 0.0f);
    x += dpp_mov<0x112>(x, 0.0f);
    x += dpp_mov<0x114>(x, 0.0f);
    x += dpp_mov<0x118>(x, 0.0f);
    x += dpp_mov<0x142>(x, 0.0f);
    x += dpp_mov<0x143>(x, 0.0f);
    return lane_bcast(x, 63);
}
__device__ __forceinline__ float lae2_2(float a, float b) {
    float m = fmaxf(a, b);
    float d = fminf(a, b) - m;
    return m + __builtin_log2f(1.0f + __builtin_exp2f(d));
}
__device__ __forceinline__ float lae3_2(float a, float b, float c) {
    float m = fmaxf(fmaxf(a, b), c);   // v_max3
    float s = __builtin_exp2f(a - m) + __builtin_exp2f(b - m) + __builtin_exp2f(c - m);
    return m + __builtin_log2f(s);
}

__global__ __launch_bounds__(256) void fused_kernel(
    const float* __restrict__ logits, const float* __restrict__ attn,
    const int* __restrict__ targets, const int* __restrict__ alens,
    const int* __restrict__ slens,   const int* __restrict__ olens,
    const int* __restrict__ step,    float* __restrict__ ws,
    float* __restrict__ out)
{
    __shared__ float buf[2][CHK][TK_];          // 40960 B
    float* red = &buf[0][0][0];                 // reused by lse/ce roles
    const int bid = blockIdx.x, tid = threadIdx.x;
    const int wid = tid >> 6, lane = tid & 63;
    unsigned* uws = (unsigned*)ws;

    if (bid < NB_REC) {
        // ---------------- CTC recursion (beta domain, log2 units) ----------
        int n = bid;
        int k = min(slens[n >> 2], TK_);
        int q = min(olens[n >> 2], TQ_);
        const float* abase = attn + (size_t)n * TQ_ * TK_;

        float a0 = NEGF, a1 = NEGF, a2 = NEGF, a3 = NEGF, a4 = NEGF, p3 = NEGF;
        if (wid != 0) {
            // producers (3 waves): preload chunk 0, pre-scaled by K2
            int p = (wid - 1) * 64 + lane;
            for (int f = p; f < CHK * 32; f += 192) {
                int r = f >> 5, c4 = (f & 31) << 2;
                float4 v = *reinterpret_cast<const float4*>(abase + (size_t)r * TK_ + c4);
                *reinterpret_cast<float4*>(&buf[0][r][c4]) =
                    make_float4(v.x * K2, v.y * K2, v.z * K2, v.w * K2);
            }
        } else {
            float x00 = abase[0];
            a0 = (lane == 0) ? -EB8 : NEGF;
            a1 = (lane == 0) ? x00 * K2 : NEGF;
        }
        __syncthreads();

        for (int c = 0; c < NCH; c++) {
            int c0 = c * CHK;
            if (c0 >= q) break;                          // uniform per block
            if (wid != 0) {
                if (c0 + CHK < q && c + 1 < NCH) {       // load chunk c+1
                    int g0 = (c + 1) * CHK;
                    float* db = &buf[(c + 1) & 1][0][0];
                    int p = (wid - 1) * 64 + lane;
                    for (int f = p; f < CHK * 32; f += 192) {
                        int r = f >> 5, c4 = (f & 31) << 2;
                        float4 v = *reinterpret_cast<const float4*>(
                            abase + (size_t)(g0 + r) * TK_ + c4);
                        *reinterpret_cast<float4*>(db + r * TK_ + c4) =
                            make_float4(v.x * K2, v.y * K2, v.z * K2, v.w * K2);
                    }
                }
            } else {
                const float* lb = &buf[c & 1][0][2 * lane];
                int lim = min(CHK, q - c0);
                int ts = (c == 0) ? 1 : 0;
#define LD(j) (*reinterpret_cast<const float2*>(lb + min((j), CHK - 1) * TK_))
#define SSTEP(xv) do {                                                        \
        float o0 = a0, o1 = a1, o2 = a2, o3 = a3;                             \
        a0 = lae2_2(o0, p3) - EB8;                                            \
        a1 = lae3_2(o1, o0, p3) + xv.x;                                       \
        a2 = lae2_2(o2, o1) - EB8;                                            \
        a3 = lae3_2(o3, o2, o1) + xv.y;                                       \
        a4 = lae2_2(a4, o3) - EB8;                                            \
        p3 = dpp_shr1_old(a3, NEGF);                                          \
    } while (0)
                float2 A = LD(ts), Bv = LD(ts + 1), Cv = LD(ts + 2), Dv = LD(ts + 3);
                for (; ts + 4 <= lim; ts += 4) {
                    float2 nA = LD(ts + 4), nB = LD(ts + 5), nC = LD(ts + 6), nD = LD(ts + 7);
                    SSTEP(A); SSTEP(Bv); SSTEP(Cv); SSTEP(Dv);
                    A = nA; Bv = nB; Cv = nC; Dv = nD;
                }
                for (; ts < lim; ts++) { SSTEP(A); A = Bv; Bv = Cv; Cv = Dv; }
#undef SSTEP
#undef LD
            }
            __syncthreads();
        }

        if (wid == 0) {
            int s1 = 2 * k - 1, s2 = 2 * k;
            float e1v, e2v;
            {
                int l = s1 >> 2, r = s1 & 3;
                float c1 = __shfl(a1, l), c3 = __shfl(a3, l);
                e1v = (r == 1) ? c1 : c3;
            }
            if (s2 == 256) {
                e2v = __shfl(a4, 63);
            } else {
                int l = s2 >> 2, r = s2 & 3;
                float c0v = __shfl(a0, l), c2v = __shfl(a2, l);
                e2v = (r == 0) ? c0v : c2v;
            }
            if (lane == 0) {
                // wait for this n's lse blocks (long done by now), read Cs
                while (__hip_atomic_load(&uws[544 + 16 * n], __ATOMIC_ACQUIRE,
                                         __HIP_MEMORY_SCOPE_AGENT) < 200u)
                    __builtin_amdgcn_s_sleep(8);
                float Cs = __hip_atomic_load(&ws[32 + 16 * n], __ATOMIC_RELAXED,
                                             __HIP_MEMORY_SCOPE_AGENT);
                float nll = -(lae2_2(e1v, e2v) + Cs) * LN2;
                float loss = nll / (float)k;
                if (!(isfinite(loss) && loss < 1.0e8f)) loss = 0.0f;
                ws[n] = loss;
            }
        }
    } else if (bid < NB_REC + NB_LSE) {
        // ---------------- lse rows: accumulate Cs[n] = sum_{t<q} lneg ------
        int li = bid - NB_REC;
        int n = li / 200, j = li % 200;
        int t = j * 4 + wid;
        int k = min(slens[n >> 2], TK_);
        int q = min(olens[n >> 2], TQ_);

        const float2 x = *reinterpret_cast<const float2*>(
            attn + ((size_t)n * TQ_ + t) * TK_ + 2 * lane);
        float xx = x.x * K2, xy = x.y * K2;
        int j0 = 2 * lane + 1, j1 = 2 * lane + 2;

        float m = (lane == 0) ? -EB8 : FNEGINF;
        if (j0 <= k) m = fmaxf(m, xx);
        if (j1 <= k) m = fmaxf(m, xy);
        m = wave_max(m);

        float s = (lane == 0) ? __builtin_exp2f(-EB8 - m) : 0.0f;
        if (j0 <= k) s += __builtin_exp2f(xx - m);
        if (j1 <= k) s += __builtin_exp2f(xy - m);
        s = wave_sum(s);

        if (lane == 0)
            red[wid] = (t < q) ? -(m + __builtin_log2f(s)) : 0.0f;
        __syncthreads();
        if (tid == 0) {
            atomicAdd(&ws[32 + 16 * n], red[0] + red[1] + red[2] + red[3]);
            __threadfence();
            __hip_atomic_fetch_add(&uws[544 + 16 * n], 1u, __ATOMIC_RELEASE,
                                   __HIP_MEMORY_SCOPE_AGENT);
        }
    } else {
        // ---------------- CE rows ------------------------------------------
        int row = (bid - NB_REC - NB_LSE) * 4 + wid;
        const float* p = logits + (size_t)row * V_TOTAL + V_TEXT;

        float4 v0 = *reinterpret_cast<const float4*>(p + lane * 4);
        float4 v1 = *reinterpret_cast<const float4*>(p + lane * 4 + 1024);
        float4 v2 = *reinterpret_cast<const float4*>(p + lane * 4 + 2048);
        float4 v3 = *reinterpret_cast<const float4*>(p + lane * 4 + 3072);
        int tg = targets[row];

        float m = fmaxf(fmaxf(fmaxf(v0.x, v0.y), fmaxf(v0.z, v0.w)),
                        fmaxf(fmaxf(v1.x, v1.y), fmaxf(v1.z, v1.w)));
        m = fmaxf(m, fmaxf(fmaxf(v2.x, v2.y), fmaxf(v2.z, v2.w)));
        m = fmaxf(m, fmaxf(fmaxf(v3.x, v3.y), fmaxf(v3.z, v3.w)));
        m = wave_max(m);

        float mn = -m * K2;
        float s =
          __builtin_exp2f(__builtin_fmaf(v0.x,K2,mn)) + __builtin_exp2f(__builtin_fmaf(v0.y,K2,mn))
        + __builtin_exp2f(__builtin_fmaf(v0.z,K2,mn)) + __builtin_exp2f(__builtin_fmaf(v0.w,K2,mn))
        + __builtin_exp2f(__builtin_fmaf(v1.x,K2,mn)) + __builtin_exp2f(__builtin_fmaf(v1.y,K2,mn))
        + __builtin_exp2f(__builtin_fmaf(v1.z,K2,mn)) + __builtin_exp2f(__builtin_fmaf(v1.w,K2,mn))
        + __builtin_exp2f(__builtin_fmaf(v2.x,K2,mn)) + __builtin_exp2f(__builtin_fmaf(v2.y,K2,mn))
        + __builtin_exp2f(__builtin_fmaf(v2.z,K2,mn)) + __builtin_exp2f(__builtin_fmaf(v2.w,K2,mn))
        + __builtin_exp2f(__builtin_fmaf(v3.x,K2,mn)) + __builtin_exp2f(__builtin_fmaf(v3.y,K2,mn))
        + __builtin_exp2f(__builtin_fmaf(v3.z,K2,mn)) + __builtin_exp2f(__builtin_fmaf(v3.w,K2,mn));
        s = wave_sum(s);

        if (lane == 0) {
            float lse = m + __builtin_log2f(s) * LN2;
            int b = row >> 10, t = row & (T_TOK - 1);
            bool valid = (t < alens[b]) && (tg != -100);
            float nll = 0.0f;
            if (valid) {
                int idx = min(max(tg - V_TEXT, 0), V_AUDIO - 1);
                nll = lse - p[idx];
            }
            red[wid] = nll;
        }
        __syncthreads();
        if (tid == 0)
            atomicAdd(&ws[1056 + 16 * (bid & 31)], red[0] + red[1] + red[2] + red[3]);
    }

    // ---------------- last-block finalize ----------------
    __syncthreads();
    if (tid == 0) {
        __threadfence();
        unsigned prev = __hip_atomic_fetch_add(&uws[1568], 1u, __ATOMIC_ACQ_REL,
                                               __HIP_MEMORY_SCOPE_AGENT);
        if (prev == (unsigned)(NB_TOT - 1)) {
            __threadfence();
            float ce_sum = 0.0f;
            for (int i = 0; i < 32; i++) ce_sum += ws[1056 + 16 * i];
            int denom = 0;
            for (int b = 0; b < B_; b++) denom += min(alens[b], T_TOK);
            denom = max(denom, 1);
            float token = ce_sum / (float)denom;
            float a = 0.0f;
            for (int i = 0; i < NSEQ; i++) a += ws[i];
            a *= (1.0f / NSEQ);
            if (step[0] <= 5000) a = 0.0f;
            out[0] = 1.5f * token + 10.0f * a;
            out[1] = a;
            out[2] = token;
        }
    }
}

extern "C" void kernel_launch(void* const* d_in, const int* in_sizes, int n_in,
                              void* d_out, int out_size, void* d_ws, size_t ws_size,
                              hipStream_t stream)
{
    const float* logits  = (const float*)d_in[0];
    const float* attn    = (const float*)d_in[1];
    const int*   targets = (const int*)d_in[2];
    const int*   alens   = (const int*)d_in[3];
    const int*   slens   = (const int*)d_in[4];
    const int*   olens   = (const int*)d_in[5];
    const int*   step    = (const int*)d_in[6];
    float* out = (float*)d_out;
    float* ws  = (float*)d_ws;

    hipMemsetAsync(d_ws, 0, 6400, stream);   // zero atomics/counters region
    fused_kernel<<<dim3(NB_TOT), dim3(256), 0, stream>>>(
        logits, attn, targets, alens, slens, olens, step, ws, out);
}